// Round 4
// baseline (341.327 us; speedup 1.0000x reference)
//
#include <hip/hip_runtime.h>

#define MBLK 32

typedef __attribute__((ext_vector_type(8))) short bf16x8;
typedef __attribute__((ext_vector_type(4))) short bf16x4;
typedef __attribute__((ext_vector_type(4))) float f32x4;

__device__ __forceinline__ unsigned short f2bf(float x){
  unsigned int u = __float_as_uint(x);
  u = u + 0x7FFFu + ((u >> 16) & 1u);
  return (unsigned short)(u >> 16);
}
__device__ __forceinline__ float bf2f(unsigned short s){
  return __uint_as_float(((unsigned int)s) << 16);
}
__device__ __forceinline__ float sigm(float x){
  return __builtin_amdgcn_rcpf(1.0f + __expf(-x));
}
__device__ __forceinline__ float tanh_(float x){
  return 1.0f - 2.0f*__builtin_amdgcn_rcpf(__expf(2.0f*x) + 1.0f);
}
// pack 2 f32 -> 2 bf16 (RNE), lo = first operand
__device__ __forceinline__ unsigned int pk_bf16(float lo, float hi){
  unsigned int r;
  asm("v_cvt_pk_bf16_f32 %0, %1, %2" : "=v"(r) : "v"(lo), "v"(hi));
  return r;
}

// 1024-thread block, 16 waves, MBLK=32, 256 blocks = 1 block/CU,
// __launch_bounds__(1024,4) -> <=128 VGPR -> 4 waves/SIMD.
// Weight B-frags Bf[2][6] = 48 VGPR/thread. Gate split: tile n2, lane i ->
// gate n2*2+(i&1), hidden wv*8+(i>>1); lane pairs i/i^1 exchange
// complementary gates via shfl_xor(.,1) (quad DPP).
// vs round 3 (LDS-flood attack):
//  - ALL loop-invariant LDS reads hoisted to registers (bias, eW/eb slice,
//    pred_W rows, imgc, pb); biasL/pwL/eW0/eW1/ebL LDS arrays deleted.
//  - h2 write: in-register 4x8 transpose (cvt_pk pack -> shfl_xor(2)+
//    v_perm -> shfl_xor(4)+sel) so each lane does ONE ds_write_b64 of
//    4 consecutive hidden for one sample (was 4 scalar b16, 8 lanes/bank).
//  - obs masked-keep via registers (oldP0/1) -> zero LDS reads.
// Double-buffered [x(64)|h(128)] bf16 tile, row stride 200 shorts
// (25 x 16B -> A-frag b128 reads span-balanced across banks).
__global__ __launch_bounds__(1024, 4) void traj_kernel(
    const float* __restrict__ img, const float* __restrict__ obs_pos,
    const int* __restrict__ hist, const float* __restrict__ rel,
    const float* __restrict__ h0, const float* __restrict__ W_ih,
    const float* __restrict__ W_hh, const float* __restrict__ b_ih,
    const float* __restrict__ b_hh, const float* __restrict__ eW,
    const float* __restrict__ eb, const float* __restrict__ pW,
    const float* __restrict__ pb, float* __restrict__ out)
{
  __shared__ unsigned short xh[2][MBLK*200];
  __shared__ float relL[MBLK*40];
  __shared__ float imgcL[MBLK*2];

  const int tid  = threadIdx.x;
  const int wv   = tid >> 6;           // 0..15
  const int lane = tid & 63;
  const int q    = lane >> 4;
  const int i    = lane & 15;
  const int par  = i & 1;              // gate parity / mt half
  const int jj   = i >> 1;             // 0..7 (hidden within wave)
  const int j    = wv*8 + jj;          // hidden unit owned by this lane
  const int jj2  = jj >> 2;
  const int g0   = blockIdx.x * MBLK;
  const int dm   = tid >> 5;           // sample 0..31 (32 threads/sample)
  const int i32  = tid & 31;

  // post-transpose identity: this lane writes hidden quad hq..hq+3 of m_post
  const int m_post = par*16 + q*4 + (jj & 3);
  const int hq     = wv*8 + jj2*4;
  const int wofs   = m_post*200 + 64 + hq;      // shorts
  const unsigned int selA = (jj & 1) ? 0x03020706u : 0x05040100u;

  // ---- cooperative staging (only relL lives in LDS now) ----
  for (int idx = tid; idx < MBLK*40; idx += 1024) relL[idx] = rel[g0*40 + idx];

  // ---- img_embedding @ pred_W[:,128:].T  (once; constant over pred steps) ----
  {
    const float* row = img + (size_t)(g0 + dm)*2048 + i32*64;
    const float* p0  = pW + 128 + i32*64;
    const float* p1  = pW + 2176 + 128 + i32*64;
    float s0 = 0.f, s1 = 0.f;
    #pragma unroll
    for (int v = 0; v < 16; v++){
      float4 a  = ((const float4*)row)[v];
      float4 w0 = ((const float4*)p0)[v];
      float4 w1 = ((const float4*)p1)[v];
      s0 += a.x*w0.x + a.y*w0.y + a.z*w0.z + a.w*w0.w;
      s1 += a.x*w1.x + a.y*w1.y + a.z*w1.z + a.w*w1.w;
    }
    #pragma unroll
    for (int msk = 1; msk < 32; msk <<= 1){
      s0 += __shfl_xor(s0, msk);
      s1 += __shfl_xor(s1, msk);
    }
    if (i32 == 0){ imgcL[dm*2] = s0; imgcL[dm*2+1] = s1; }
  }

  // ---- hoisted loop-invariant scalars (registers, not LDS) ----
  const float bv0 = b_ih[par*128 + j]       + b_hh[par*128 + j];
  const float bv1 = b_ih[(2 + par)*128 + j] + b_hh[(2 + par)*128 + j];
  const int   e0  = i32*2;                  // embed dims owned in x_emb phases
  const float wA0 = eW[e0*2],     wB0 = eW[e0*2 + 1];
  const float wA1 = eW[(e0+1)*2], wB1 = eW[(e0+1)*2 + 1];
  const float be0 = eb[e0],       be1 = eb[e0+1];
  const float pb0 = pb[0],        pb1 = pb[1];
  float pwa0 = pW[i32*4+0], pwa1 = pW[i32*4+1], pwa2 = pW[i32*4+2], pwa3 = pW[i32*4+3];
  float pwb0 = pW[2176+i32*4+0], pwb1 = pW[2176+i32*4+1], pwb2 = pW[2176+i32*4+2], pwb3 = pW[2176+i32*4+3];

  // ---- per-lane persistent state ----
  float h0j = h0[j];
  unsigned int thrpk = 0;              // 4 x (20 - hist) for c-mask (pre-transpose samples)
  float c_s[4];
  #pragma unroll
  for (int r = 0; r < 4; r++){
    int m = par*16 + q*4 + r;
    thrpk |= ((unsigned int)((20 - hist[g0 + m]) & 0xFF)) << (8*r);
    c_s[r] = h0j;
    xh[0][m*200 + 64 + j] = f2bf(h0j);
  }
  const int thr_post = 20 - hist[g0 + m_post];      // h-mask (post-transpose sample)
  unsigned int oldP0 = pk_bf16(h0[hq],   h0[hq+1]); // packed h currently in LDS slots
  unsigned int oldP1 = pk_bf16(h0[hq+2], h0[hq+3]);

  // ---- weight B-fragments, fp32 -> bf16, register-resident (48 VGPR) ----
  bf16x8 Bf[2][6];
  #pragma unroll
  for (int n2 = 0; n2 < 2; n2++){
    int row = (n2*2 + par)*128 + j;
    #pragma unroll
    for (int kt = 0; kt < 6; kt++){
      const float* src = (kt < 2) ? (W_ih + row*64  + kt*32      + q*8)
                                  : (W_hh + row*128 + (kt-2)*32  + q*8);
      float4 lo = ((const float4*)src)[0];
      float4 hi = ((const float4*)src)[1];
      bf16x8 tf;
      tf[0]=(short)f2bf(lo.x); tf[1]=(short)f2bf(lo.y); tf[2]=(short)f2bf(lo.z); tf[3]=(short)f2bf(lo.w);
      tf[4]=(short)f2bf(hi.x); tf[5]=(short)f2bf(hi.y); tf[6]=(short)f2bf(hi.z); tf[7]=(short)f2bf(hi.w);
      Bf[n2][kt] = tf;
    }
  }

  float pos_r = 0.f;
  if (i32 < 2) pos_r = obs_pos[(size_t)(g0 + dm)*40 + 38 + i32];

  __syncthreads();   // staging (relL, imgcL) visible

  const float imgc0 = imgcL[dm*2], imgc1 = imgcL[dm*2+1];

  // ---- x_emb(t=1) into xh[0] ----
  {
    float2 rr = *((const float2*)&relL[dm*40 + 2]);
    float a0 = fmaxf(0.f, rr.x*wA0 + rr.y*wB0 + be0);
    float a1 = fmaxf(0.f, rr.x*wA1 + rr.y*wB1 + be1);
    *((unsigned int*)&xh[0][dm*200 + e0]) = pk_bf16(a0, a1);
  }

  int b = 0;

  for (int step = 0; step < 49; step++){
    const bool obs = (step < 19);
    __syncthreads();     // prev step's writes into xh[b] visible

    if (!obs){
      // ---- disp = h @ pred_W[:, :128].T + imgc + pb ; 32 threads/sample ----
      bf16x4 hv = *((const bf16x4*)&xh[b][dm*200 + 64 + i32*4]);
      float h0f = bf2f((unsigned short)hv[0]);
      float h1f = bf2f((unsigned short)hv[1]);
      float h2f_ = bf2f((unsigned short)hv[2]);
      float h3f = bf2f((unsigned short)hv[3]);
      float s0 = h0f*pwa0 + h1f*pwa1 + h2f_*pwa2 + h3f*pwa3;
      float s1 = h0f*pwb0 + h1f*pwb1 + h2f_*pwb2 + h3f*pwb3;
      s0 += __shfl_xor(s0, 1);  s1 += __shfl_xor(s1, 1);
      s0 += __shfl_xor(s0, 2);  s1 += __shfl_xor(s1, 2);
      s0 += __shfl_xor(s0, 4);  s1 += __shfl_xor(s1, 4);
      s0 += __shfl_xor(s0, 8);  s1 += __shfl_xor(s1, 8);
      s0 += __shfl_xor(s0, 16); s1 += __shfl_xor(s1, 16);
      float d0 = s0 + imgc0 + pb0;
      float d1 = s1 + imgc1 + pb1;
      if (i32 < 2){
        pos_r += (i32 == 0) ? d0 : d1;
        out[(size_t)(g0 + dm)*60 + (size_t)(step - 19)*2 + i32] = pos_r;
      }
      float a0 = fmaxf(0.f, d0*wA0 + d1*wB0 + be0);
      float a1 = fmaxf(0.f, d0*wA1 + d1*wB1 + be1);
      *((unsigned int*)&xh[b][dm*200 + e0]) = pk_bf16(a0, a1);
      __syncthreads();   // x_emb visible before MFMA reads
    }

    // ---- gates = [x|h] @ [W_ih|W_hh].T + b  via MFMA 16x16x32 bf16 ----
    f32x4 a00 = (f32x4){bv0, bv0, bv0, bv0};
    f32x4 a01 = (f32x4){bv1, bv1, bv1, bv1};
    f32x4 a10 = a00;
    f32x4 a11 = a01;
    {
      bf16x8 A[6];
      #pragma unroll
      for (int kt = 0; kt < 6; kt++)
        A[kt] = *((const bf16x8*)&xh[b][i*200 + kt*32 + q*8]);
      #pragma unroll
      for (int kt = 0; kt < 6; kt++){
        a00 = __builtin_amdgcn_mfma_f32_16x16x32_bf16(A[kt], Bf[0][kt], a00, 0, 0, 0);
        a01 = __builtin_amdgcn_mfma_f32_16x16x32_bf16(A[kt], Bf[1][kt], a01, 0, 0, 0);
      }
    }
    {
      bf16x8 A[6];
      #pragma unroll
      for (int kt = 0; kt < 6; kt++)
        A[kt] = *((const bf16x8*)&xh[b][(16 + i)*200 + kt*32 + q*8]);
      #pragma unroll
      for (int kt = 0; kt < 6; kt++){
        a10 = __builtin_amdgcn_mfma_f32_16x16x32_bf16(A[kt], Bf[0][kt], a10, 0, 0, 0);
        a11 = __builtin_amdgcn_mfma_f32_16x16x32_bf16(A[kt], Bf[1][kt], a11, 0, 0, 0);
      }
    }

    // ---- obs: next step's x_emb (depends only on relL) -> xh[b^1] ----
    if (obs && step < 18){
      int tt = step + 2;               // t+1
      float2 rr = *((const float2*)&relL[dm*40 + tt*2]);
      float a0 = fmaxf(0.f, rr.x*wA0 + rr.y*wB0 + be0);
      float a1 = fmaxf(0.f, rr.x*wA1 + rr.y*wB1 + be1);
      *((unsigned int*)&xh[b^1][dm*200 + e0]) = pk_bf16(a0, a1);
    }

    // ---- par-selection via vector ternaries (static indexing only) ----
    f32x4 self0 = par ? a10 : a00;
    f32x4 self1 = par ? a11 : a01;
    f32x4 send0 = par ? a00 : a10;
    f32x4 send1 = par ? a01 : a11;

    // ---- gate exchange (lanes i <-> i^1) + nonlinearity; h2 -> h2f[] ----
    float h2f[4];
    #pragma unroll
    for (int r = 0; r < 4; r++){
      float y0 = __shfl_xor(send0[r], 1);
      float y1 = __shfl_xor(send1[r], 1);
      float a0 = self0[r];
      float a1 = self1[r];
      float ig = par ? y0 : a0;
      float fg = par ? a0 : y0;
      float gg = par ? y1 : a1;
      float og = par ? a1 : y1;
      float c2 = sigm(fg)*c_s[r] + sigm(ig)*tanh_(gg);
      float h2 = sigm(og)*tanh_(c2);
      if (obs){
        int thr = (int)((thrpk >> (8*r)) & 0xFFu);
        if (step < thr) c2 = c_s[r];           // c masked-keep (per pre-transpose sample)
      }
      c_s[r] = c2;
      h2f[r] = h2;
    }

    // ---- 4x8 in-register transpose: lane ends with 4 consecutive hidden
    //      (hq..hq+3) of ONE sample (m_post) -> single ds_write_b64 ----
    unsigned int P0 = pk_bf16(h2f[0], h2f[1]);
    unsigned int P1 = pk_bf16(h2f[2], h2f[3]);
    unsigned int X0 = __shfl_xor(P0, 2);
    unsigned int X1 = __shfl_xor(P1, 2);
    P0 = __builtin_amdgcn_perm(X0, P0, selA);
    P1 = __builtin_amdgcn_perm(X1, P1, selA);
    unsigned int Z0 = __shfl_xor(P0, 4);
    unsigned int Z1 = __shfl_xor(P1, 4);
    unsigned int Q0 = (jj & 2) ? Z1 : P0;
    unsigned int Q1 = (jj & 2) ? P1 : Z0;
    if (obs){
      // h masked-keep: per-sample bool, old packed value tracked in regs
      bool keep = (step < thr_post);
      Q0 = keep ? oldP0 : Q0;
      Q1 = keep ? oldP1 : Q1;
      oldP0 = Q0; oldP1 = Q1;
    }
    *((uint2*)&xh[b^1][wofs]) = make_uint2(Q0, Q1);

    b ^= 1;
  }
}

extern "C" void kernel_launch(void* const* d_in, const int* in_sizes, int n_in,
                              void* d_out, int out_size, void* d_ws, size_t ws_size,
                              hipStream_t stream){
  const float* img     = (const float*)d_in[0];
  const float* obs_pos = (const float*)d_in[1];
  const int*   hist    = (const int*)d_in[2];
  const float* rel     = (const float*)d_in[3];
  const float* h0      = (const float*)d_in[4];
  const float* W_ih    = (const float*)d_in[5];
  const float* W_hh    = (const float*)d_in[6];
  const float* b_ih    = (const float*)d_in[7];
  const float* b_hh    = (const float*)d_in[8];
  const float* eW      = (const float*)d_in[9];
  const float* eb      = (const float*)d_in[10];
  const float* pW      = (const float*)d_in[11];
  const float* pb      = (const float*)d_in[12];
  float* out = (float*)d_out;
  hipLaunchKernelGGL(traj_kernel, dim3(8192/MBLK), dim3(1024), 0, stream,
                     img, obs_pos, hist, rel, h0, W_ih, W_hh, b_ih, b_hh,
                     eW, eb, pW, pb, out);
}

// Round 5
// 321.253 us; speedup vs baseline: 1.0625x; 1.0625x over previous
//
#include <hip/hip_runtime.h>

#define MBLK 32

typedef __attribute__((ext_vector_type(8))) short bf16x8;
typedef __attribute__((ext_vector_type(4))) short bf16x4;
typedef __attribute__((ext_vector_type(4))) float f32x4;

__device__ __forceinline__ unsigned short f2bf(float x){
  unsigned int u = __float_as_uint(x);
  u = u + 0x7FFFu + ((u >> 16) & 1u);
  return (unsigned short)(u >> 16);
}
__device__ __forceinline__ float bf2f(unsigned short s){
  return __uint_as_float(((unsigned int)s) << 16);
}
// Pade (Lambert CF depth-5): tanh x ~ x(945+105u+u^2)/(945+420u+15u^2), u=x^2.
// Max abs err ~1.4e-3 (with +-1 clamp) -- below bf16 h-storage granularity.
// 1 trans (rcp) instead of 2 (exp+rcp): halves the trans-pipe load.
__device__ __forceinline__ float tanhP(float x){
  float u = x*x;
  float num = fmaf(u, fmaf(u, 1.0f, 105.0f), 945.0f);
  float den = fmaf(u, fmaf(u, 15.0f, 420.0f), 945.0f);
  float t = x*num*__builtin_amdgcn_rcpf(den);
  return fminf(1.0f, fmaxf(-1.0f, t));     // v_med3
}
__device__ __forceinline__ float sigmP(float x){
  return fmaf(0.5f, tanhP(0.5f*x), 0.5f);  // sigma(x)=0.5+0.5*tanh(x/2)
}
// pack 2 f32 -> 2 bf16 (RNE), lo = first operand
__device__ __forceinline__ unsigned int pk_bf16(float lo, float hi){
  unsigned int r;
  asm("v_cvt_pk_bf16_f32 %0, %1, %2" : "=v"(r) : "v"(lo), "v"(hi));
  return r;
}

// 1024-thread block, 16 waves, MBLK=32, 256 blocks = 1 block/CU,
// __launch_bounds__(1024,4) -> <=128 VGPR -> 4 waves/SIMD.
// Weight B-frags Bf[2][6] = 48 VGPR/thread. Gate split: tile n2, lane i ->
// gate n2*2+(i&1), hidden wv*8+(i>>1); lane pairs i/i^1 exchange
// complementary gates via shfl_xor(.,1).
// vs round 4 (spill fix + trans halving):
//  - eW/eb/pW/pb invariants BACK IN LDS (round-4 reg-hoist spilled: WRITE
//    27.7->79.5MB). pW read as 2x float4 per pred step (was 8 scalars).
//  - KEEP: pk_bf16, in-register 4x8 transpose -> single ds_write_b64 h
//    update, register masked-keep (oldP0/1) -- round 4 verified these.
//  - Pade nonlinearities: 1 trans per sigm/tanh instead of 2.
__global__ __launch_bounds__(1024, 4) void traj_kernel(
    const float* __restrict__ img, const float* __restrict__ obs_pos,
    const int* __restrict__ hist, const float* __restrict__ rel,
    const float* __restrict__ h0, const float* __restrict__ W_ih,
    const float* __restrict__ W_hh, const float* __restrict__ b_ih,
    const float* __restrict__ b_hh, const float* __restrict__ eW,
    const float* __restrict__ eb, const float* __restrict__ pW,
    const float* __restrict__ pb, float* __restrict__ out)
{
  __shared__ unsigned short xh[2][MBLK*200];
  __shared__ float relL[MBLK*40];
  __shared__ float pwL[256];          // pred_W[:, :128]
  __shared__ float eW0[64], eW1[64], ebL[64];
  __shared__ float imgcL[MBLK*2];
  __shared__ float pbL[2];

  const int tid  = threadIdx.x;
  const int wv   = tid >> 6;           // 0..15
  const int lane = tid & 63;
  const int q    = lane >> 4;
  const int i    = lane & 15;
  const int par  = i & 1;              // gate parity / mt half
  const int jj   = i >> 1;             // 0..7 (hidden within wave)
  const int j    = wv*8 + jj;          // hidden unit owned by this lane
  const int jj2  = jj >> 2;
  const int g0   = blockIdx.x * MBLK;
  const int dm   = tid >> 5;           // sample 0..31 (32 threads/sample)
  const int i32  = tid & 31;

  // post-transpose identity: this lane writes hidden quad hq..hq+3 of m_post
  const int m_post = par*16 + q*4 + (jj & 3);
  const int hq     = wv*8 + jj2*4;
  const int wofs   = m_post*200 + 64 + hq;      // shorts
  const unsigned int selA = (jj & 1) ? 0x03020706u : 0x05040100u;

  // ---- cooperative staging ----
  for (int idx = tid; idx < MBLK*40; idx += 1024) relL[idx] = rel[g0*40 + idx];
  if (tid < 256) pwL[tid] = pW[(tid >> 7)*2176 + (tid & 127)];
  if (tid < 64){ eW0[tid] = eW[tid*2]; eW1[tid] = eW[tid*2+1]; ebL[tid] = eb[tid]; }
  if (tid < 2) pbL[tid] = pb[tid];

  // ---- img_embedding @ pred_W[:,128:].T  (once; constant over pred steps) ----
  {
    const float* row = img + (size_t)(g0 + dm)*2048 + i32*64;
    const float* p0  = pW + 128 + i32*64;
    const float* p1  = pW + 2176 + 128 + i32*64;
    float s0 = 0.f, s1 = 0.f;
    #pragma unroll
    for (int v = 0; v < 16; v++){
      float4 a  = ((const float4*)row)[v];
      float4 w0 = ((const float4*)p0)[v];
      float4 w1 = ((const float4*)p1)[v];
      s0 += a.x*w0.x + a.y*w0.y + a.z*w0.z + a.w*w0.w;
      s1 += a.x*w1.x + a.y*w1.y + a.z*w1.z + a.w*w1.w;
    }
    #pragma unroll
    for (int msk = 1; msk < 32; msk <<= 1){
      s0 += __shfl_xor(s0, msk);
      s1 += __shfl_xor(s1, msk);
    }
    if (i32 == 0){ imgcL[dm*2] = s0; imgcL[dm*2+1] = s1; }
  }

  // ---- hoisted per-step invariants kept minimal (2 regs) ----
  const float bv0 = b_ih[par*128 + j]       + b_hh[par*128 + j];
  const float bv1 = b_ih[(2 + par)*128 + j] + b_hh[(2 + par)*128 + j];
  const int   e0  = i32*2;                  // embed dims owned in x_emb phases

  // ---- per-lane persistent state ----
  float h0j = h0[j];
  unsigned int thrpk = 0;              // 4 x (20 - hist) for c-mask
  float c_s[4];
  #pragma unroll
  for (int r = 0; r < 4; r++){
    int m = par*16 + q*4 + r;
    thrpk |= ((unsigned int)((20 - hist[g0 + m]) & 0xFF)) << (8*r);
    c_s[r] = h0j;
    xh[0][m*200 + 64 + j] = f2bf(h0j);
  }
  const int thr_post = 20 - hist[g0 + m_post];      // h-mask sample
  unsigned int oldP0 = pk_bf16(h0[hq],   h0[hq+1]); // packed h in LDS slots
  unsigned int oldP1 = pk_bf16(h0[hq+2], h0[hq+3]);

  // ---- weight B-fragments, fp32 -> bf16, register-resident (48 VGPR) ----
  bf16x8 Bf[2][6];
  #pragma unroll
  for (int n2 = 0; n2 < 2; n2++){
    int row = (n2*2 + par)*128 + j;
    #pragma unroll
    for (int kt = 0; kt < 6; kt++){
      const float* src = (kt < 2) ? (W_ih + row*64  + kt*32      + q*8)
                                  : (W_hh + row*128 + (kt-2)*32  + q*8);
      float4 lo = ((const float4*)src)[0];
      float4 hi = ((const float4*)src)[1];
      bf16x8 tf;
      tf[0]=(short)f2bf(lo.x); tf[1]=(short)f2bf(lo.y); tf[2]=(short)f2bf(lo.z); tf[3]=(short)f2bf(lo.w);
      tf[4]=(short)f2bf(hi.x); tf[5]=(short)f2bf(hi.y); tf[6]=(short)f2bf(hi.z); tf[7]=(short)f2bf(hi.w);
      Bf[n2][kt] = tf;
    }
  }

  float pos_r = 0.f;
  if (i32 < 2) pos_r = obs_pos[(size_t)(g0 + dm)*40 + 38 + i32];

  __syncthreads();   // staging visible

  const float imgc0 = imgcL[dm*2], imgc1 = imgcL[dm*2+1];

  // ---- x_emb(t=1) into xh[0] ----
  {
    float2 rr = *((const float2*)&relL[dm*40 + 2]);
    float a0 = fmaxf(0.f, rr.x*eW0[e0]   + rr.y*eW1[e0]   + ebL[e0]);
    float a1 = fmaxf(0.f, rr.x*eW0[e0+1] + rr.y*eW1[e0+1] + ebL[e0+1]);
    *((unsigned int*)&xh[0][dm*200 + e0]) = pk_bf16(a0, a1);
  }

  int b = 0;

  for (int step = 0; step < 49; step++){
    const bool obs = (step < 19);
    __syncthreads();     // prev step's writes into xh[b] visible

    if (!obs){
      // ---- disp = h @ pred_W[:, :128].T + imgc + pb ; 32 threads/sample ----
      bf16x4 hv = *((const bf16x4*)&xh[b][dm*200 + 64 + i32*4]);
      float4 pa = *((const float4*)&pwL[i32*4]);
      float4 pc = *((const float4*)&pwL[128 + i32*4]);
      float h0f = bf2f((unsigned short)hv[0]);
      float h1f = bf2f((unsigned short)hv[1]);
      float h2f_ = bf2f((unsigned short)hv[2]);
      float h3f = bf2f((unsigned short)hv[3]);
      float s0 = h0f*pa.x + h1f*pa.y + h2f_*pa.z + h3f*pa.w;
      float s1 = h0f*pc.x + h1f*pc.y + h2f_*pc.z + h3f*pc.w;
      s0 += __shfl_xor(s0, 1);  s1 += __shfl_xor(s1, 1);
      s0 += __shfl_xor(s0, 2);  s1 += __shfl_xor(s1, 2);
      s0 += __shfl_xor(s0, 4);  s1 += __shfl_xor(s1, 4);
      s0 += __shfl_xor(s0, 8);  s1 += __shfl_xor(s1, 8);
      s0 += __shfl_xor(s0, 16); s1 += __shfl_xor(s1, 16);
      float d0 = s0 + imgc0 + pbL[0];
      float d1 = s1 + imgc1 + pbL[1];
      if (i32 < 2){
        pos_r += (i32 == 0) ? d0 : d1;
        out[(size_t)(g0 + dm)*60 + (size_t)(step - 19)*2 + i32] = pos_r;
      }
      float a0 = fmaxf(0.f, d0*eW0[e0]   + d1*eW1[e0]   + ebL[e0]);
      float a1 = fmaxf(0.f, d0*eW0[e0+1] + d1*eW1[e0+1] + ebL[e0+1]);
      *((unsigned int*)&xh[b][dm*200 + e0]) = pk_bf16(a0, a1);
      __syncthreads();   // x_emb visible before MFMA reads
    }

    // ---- gates = [x|h] @ [W_ih|W_hh].T + b  via MFMA 16x16x32 bf16 ----
    f32x4 a00 = (f32x4){bv0, bv0, bv0, bv0};
    f32x4 a01 = (f32x4){bv1, bv1, bv1, bv1};
    f32x4 a10 = a00;
    f32x4 a11 = a01;
    {
      bf16x8 A[6];
      #pragma unroll
      for (int kt = 0; kt < 6; kt++)
        A[kt] = *((const bf16x8*)&xh[b][i*200 + kt*32 + q*8]);
      #pragma unroll
      for (int kt = 0; kt < 6; kt++){
        a00 = __builtin_amdgcn_mfma_f32_16x16x32_bf16(A[kt], Bf[0][kt], a00, 0, 0, 0);
        a01 = __builtin_amdgcn_mfma_f32_16x16x32_bf16(A[kt], Bf[1][kt], a01, 0, 0, 0);
      }
    }
    {
      bf16x8 A[6];
      #pragma unroll
      for (int kt = 0; kt < 6; kt++)
        A[kt] = *((const bf16x8*)&xh[b][(16 + i)*200 + kt*32 + q*8]);
      #pragma unroll
      for (int kt = 0; kt < 6; kt++){
        a10 = __builtin_amdgcn_mfma_f32_16x16x32_bf16(A[kt], Bf[0][kt], a10, 0, 0, 0);
        a11 = __builtin_amdgcn_mfma_f32_16x16x32_bf16(A[kt], Bf[1][kt], a11, 0, 0, 0);
      }
    }

    // ---- obs: next step's x_emb (depends only on relL) -> xh[b^1] ----
    if (obs && step < 18){
      int tt = step + 2;               // t+1
      float2 rr = *((const float2*)&relL[dm*40 + tt*2]);
      float a0 = fmaxf(0.f, rr.x*eW0[e0]   + rr.y*eW1[e0]   + ebL[e0]);
      float a1 = fmaxf(0.f, rr.x*eW0[e0+1] + rr.y*eW1[e0+1] + ebL[e0+1]);
      *((unsigned int*)&xh[b^1][dm*200 + e0]) = pk_bf16(a0, a1);
    }

    // ---- par-selection via vector ternaries (static indexing only) ----
    f32x4 self0 = par ? a10 : a00;
    f32x4 self1 = par ? a11 : a01;
    f32x4 send0 = par ? a00 : a10;
    f32x4 send1 = par ? a01 : a11;

    // ---- gate exchange (lanes i <-> i^1) + nonlinearity (Pade) ----
    float h2f[4];
    #pragma unroll
    for (int r = 0; r < 4; r++){
      float y0 = __shfl_xor(send0[r], 1);
      float y1 = __shfl_xor(send1[r], 1);
      float a0 = self0[r];
      float a1 = self1[r];
      float ig = par ? y0 : a0;
      float fg = par ? a0 : y0;
      float gg = par ? y1 : a1;
      float og = par ? a1 : y1;
      float c2 = sigmP(fg)*c_s[r] + sigmP(ig)*tanhP(gg);
      float h2 = sigmP(og)*tanhP(c2);
      if (obs){
        int thr = (int)((thrpk >> (8*r)) & 0xFFu);
        if (step < thr) c2 = c_s[r];           // c masked-keep
      }
      c_s[r] = c2;
      h2f[r] = h2;
    }

    // ---- 4x8 in-register transpose -> single ds_write_b64 ----
    unsigned int P0 = pk_bf16(h2f[0], h2f[1]);
    unsigned int P1 = pk_bf16(h2f[2], h2f[3]);
    unsigned int X0 = __shfl_xor(P0, 2);
    unsigned int X1 = __shfl_xor(P1, 2);
    P0 = __builtin_amdgcn_perm(X0, P0, selA);
    P1 = __builtin_amdgcn_perm(X1, P1, selA);
    unsigned int Z0 = __shfl_xor(P0, 4);
    unsigned int Z1 = __shfl_xor(P1, 4);
    unsigned int Q0 = (jj & 2) ? Z1 : P0;
    unsigned int Q1 = (jj & 2) ? P1 : Z0;
    if (obs){
      bool keep = (step < thr_post);
      Q0 = keep ? oldP0 : Q0;
      Q1 = keep ? oldP1 : Q1;
      oldP0 = Q0; oldP1 = Q1;
    }
    *((uint2*)&xh[b^1][wofs]) = make_uint2(Q0, Q1);

    b ^= 1;
  }
}

extern "C" void kernel_launch(void* const* d_in, const int* in_sizes, int n_in,
                              void* d_out, int out_size, void* d_ws, size_t ws_size,
                              hipStream_t stream){
  const float* img     = (const float*)d_in[0];
  const float* obs_pos = (const float*)d_in[1];
  const int*   hist    = (const int*)d_in[2];
  const float* rel     = (const float*)d_in[3];
  const float* h0      = (const float*)d_in[4];
  const float* W_ih    = (const float*)d_in[5];
  const float* W_hh    = (const float*)d_in[6];
  const float* b_ih    = (const float*)d_in[7];
  const float* b_hh    = (const float*)d_in[8];
  const float* eW      = (const float*)d_in[9];
  const float* eb      = (const float*)d_in[10];
  const float* pW      = (const float*)d_in[11];
  const float* pb      = (const float*)d_in[12];
  float* out = (float*)d_out;
  hipLaunchKernelGGL(traj_kernel, dim3(8192/MBLK), dim3(1024), 0, stream,
                     img, obs_pos, hist, rel, h0, W_ih, W_hh, b_ih, b_hh,
                     eW, eb, pW, pb, out);
}

// Round 6
// 296.902 us; speedup vs baseline: 1.1496x; 1.0820x over previous
//
#include <hip/hip_runtime.h>

#define MBLK 32

typedef __attribute__((ext_vector_type(8))) short bf16x8;
typedef __attribute__((ext_vector_type(4))) short bf16x4;
typedef __attribute__((ext_vector_type(4))) float f32x4;

__device__ __forceinline__ unsigned short f2bf(float x){
  unsigned int u = __float_as_uint(x);
  u = u + 0x7FFFu + ((u >> 16) & 1u);
  return (unsigned short)(u >> 16);
}
__device__ __forceinline__ float bf2f(unsigned short s){
  return __uint_as_float(((unsigned int)s) << 16);
}
__device__ __forceinline__ float sigm(float x){
  return __builtin_amdgcn_rcpf(1.0f + __expf(-x));
}
__device__ __forceinline__ float tanh_(float x){
  return 1.0f - 2.0f*__builtin_amdgcn_rcpf(__expf(2.0f*x) + 1.0f);
}
// pack 2 f32 -> 2 bf16 (RNE), lo = first operand
__device__ __forceinline__ unsigned int pk_bf16(float lo, float hi){
  unsigned int r;
  asm("v_cvt_pk_bf16_f32 %0, %1, %2" : "=v"(r) : "v"(lo), "v"(hi));
  return r;
}

// 1024-thread block, 16 waves, MBLK=32, 256 blocks = 1 block/CU,
// __launch_bounds__(1024,4) -> <=128 VGPR -> 4 waves/SIMD.
// Weight B-frags Bf[2][6] = 48 VGPR/thread. Gate split: tile n2, lane i ->
// gate n2*2+(i&1), hidden wv*8+(i>>1); lane pairs i/i^1 exchange
// complementary gates via shfl_xor(.,1).
// vs round 5:
//  - Padé REVERTED to exp-based nonlin (r5: VALU busy-cy/step +22%, dur
//    226->245.6us -- v_exp is cheap on gfx950, Padé's 9 VALU ops are not).
//  - KEEP: pk_bf16 + in-register 4x8 transpose -> single ds_write_b64 h
//    update (conflicts 12.4M->10.5M).
//  - masked-keep h re-reads old pair from xh[b][wofs] (obs-only b64 read)
//    instead of persistent oldP0/1 regs (-2 VGPR, kills r5 spill).
//  - PRED-STEP SPLIT: after barrier1, h-frag reads + 16 W_hh MFMAs overlap
//    the disp reduce; only the x-part (4 reads, 8 MFMAs) waits on barrier2.
// Double-buffered [x(64)|h(128)] bf16 tile, row stride 200 shorts.
__global__ __launch_bounds__(1024, 4) void traj_kernel(
    const float* __restrict__ img, const float* __restrict__ obs_pos,
    const int* __restrict__ hist, const float* __restrict__ rel,
    const float* __restrict__ h0, const float* __restrict__ W_ih,
    const float* __restrict__ W_hh, const float* __restrict__ b_ih,
    const float* __restrict__ b_hh, const float* __restrict__ eW,
    const float* __restrict__ eb, const float* __restrict__ pW,
    const float* __restrict__ pb, float* __restrict__ out)
{
  __shared__ unsigned short xh[2][MBLK*200];
  __shared__ float relL[MBLK*40];
  __shared__ float pwL[256];          // pred_W[:, :128]
  __shared__ float eW0[64], eW1[64], ebL[64];
  __shared__ float imgcL[MBLK*2];
  __shared__ float pbL[2];

  const int tid  = threadIdx.x;
  const int wv   = tid >> 6;           // 0..15
  const int lane = tid & 63;
  const int q    = lane >> 4;
  const int i    = lane & 15;
  const int par  = i & 1;              // gate parity / mt half
  const int jj   = i >> 1;             // 0..7 (hidden within wave)
  const int j    = wv*8 + jj;          // hidden unit owned by this lane
  const int jj2  = jj >> 2;
  const int g0   = blockIdx.x * MBLK;
  const int dm   = tid >> 5;           // sample 0..31 (32 threads/sample)
  const int i32  = tid & 31;

  // post-transpose identity: this lane writes hidden quad hq..hq+3 of m_post
  const int m_post = par*16 + q*4 + (jj & 3);
  const int hq     = wv*8 + jj2*4;
  const int wofs   = m_post*200 + 64 + hq;      // shorts
  const unsigned int selA = (jj & 1) ? 0x03020706u : 0x05040100u;

  // ---- cooperative staging ----
  for (int idx = tid; idx < MBLK*40; idx += 1024) relL[idx] = rel[g0*40 + idx];
  if (tid < 256) pwL[tid] = pW[(tid >> 7)*2176 + (tid & 127)];
  if (tid < 64){ eW0[tid] = eW[tid*2]; eW1[tid] = eW[tid*2+1]; ebL[tid] = eb[tid]; }
  if (tid < 2) pbL[tid] = pb[tid];

  // ---- img_embedding @ pred_W[:,128:].T  (once; constant over pred steps) ----
  {
    const float* row = img + (size_t)(g0 + dm)*2048 + i32*64;
    const float* p0  = pW + 128 + i32*64;
    const float* p1  = pW + 2176 + 128 + i32*64;
    float s0 = 0.f, s1 = 0.f;
    #pragma unroll
    for (int v = 0; v < 16; v++){
      float4 a  = ((const float4*)row)[v];
      float4 w0 = ((const float4*)p0)[v];
      float4 w1 = ((const float4*)p1)[v];
      s0 += a.x*w0.x + a.y*w0.y + a.z*w0.z + a.w*w0.w;
      s1 += a.x*w1.x + a.y*w1.y + a.z*w1.z + a.w*w1.w;
    }
    #pragma unroll
    for (int msk = 1; msk < 32; msk <<= 1){
      s0 += __shfl_xor(s0, msk);
      s1 += __shfl_xor(s1, msk);
    }
    if (i32 == 0){ imgcL[dm*2] = s0; imgcL[dm*2+1] = s1; }
  }

  // ---- hoisted per-step invariants kept minimal (2 regs) ----
  const float bv0 = b_ih[par*128 + j]       + b_hh[par*128 + j];
  const float bv1 = b_ih[(2 + par)*128 + j] + b_hh[(2 + par)*128 + j];
  const int   e0  = i32*2;                  // embed dims owned in x_emb phases

  // ---- per-lane persistent state ----
  float h0j = h0[j];
  unsigned int thrpk = 0;              // 4 x (20 - hist) for c-mask
  float c_s[4];
  #pragma unroll
  for (int r = 0; r < 4; r++){
    int m = par*16 + q*4 + r;
    thrpk |= ((unsigned int)((20 - hist[g0 + m]) & 0xFF)) << (8*r);
    c_s[r] = h0j;
    xh[0][m*200 + 64 + j] = f2bf(h0j);
  }
  const int thr_post = 20 - hist[g0 + m_post];      // h-mask sample

  // ---- weight B-fragments, fp32 -> bf16, register-resident (48 VGPR) ----
  bf16x8 Bf[2][6];
  #pragma unroll
  for (int n2 = 0; n2 < 2; n2++){
    int row = (n2*2 + par)*128 + j;
    #pragma unroll
    for (int kt = 0; kt < 6; kt++){
      const float* src = (kt < 2) ? (W_ih + row*64  + kt*32      + q*8)
                                  : (W_hh + row*128 + (kt-2)*32  + q*8);
      float4 lo = ((const float4*)src)[0];
      float4 hi = ((const float4*)src)[1];
      bf16x8 tf;
      tf[0]=(short)f2bf(lo.x); tf[1]=(short)f2bf(lo.y); tf[2]=(short)f2bf(lo.z); tf[3]=(short)f2bf(lo.w);
      tf[4]=(short)f2bf(hi.x); tf[5]=(short)f2bf(hi.y); tf[6]=(short)f2bf(hi.z); tf[7]=(short)f2bf(hi.w);
      Bf[n2][kt] = tf;
    }
  }

  float pos_r = 0.f;
  if (i32 < 2) pos_r = obs_pos[(size_t)(g0 + dm)*40 + 38 + i32];

  __syncthreads();   // staging visible

  const float imgc0 = imgcL[dm*2], imgc1 = imgcL[dm*2+1];

  // ---- x_emb(t=1) into xh[0] ----
  {
    float2 rr = *((const float2*)&relL[dm*40 + 2]);
    float a0 = fmaxf(0.f, rr.x*eW0[e0]   + rr.y*eW1[e0]   + ebL[e0]);
    float a1 = fmaxf(0.f, rr.x*eW0[e0+1] + rr.y*eW1[e0+1] + ebL[e0+1]);
    *((unsigned int*)&xh[0][dm*200 + e0]) = pk_bf16(a0, a1);
  }

  int b = 0;

  for (int step = 0; step < 49; step++){
    const bool obs = (step < 19);
    __syncthreads();     // barrier1: prev step's writes into xh[b] visible

    f32x4 a00 = (f32x4){bv0, bv0, bv0, bv0};
    f32x4 a01 = (f32x4){bv1, bv1, bv1, bv1};
    f32x4 a10 = a00;
    f32x4 a11 = a01;

    if (obs){
      // ---- full 6-kt MFMA sweep (x written previous step) ----
      {
        bf16x8 A[6];
        #pragma unroll
        for (int kt = 0; kt < 6; kt++)
          A[kt] = *((const bf16x8*)&xh[b][i*200 + kt*32 + q*8]);
        #pragma unroll
        for (int kt = 0; kt < 6; kt++){
          a00 = __builtin_amdgcn_mfma_f32_16x16x32_bf16(A[kt], Bf[0][kt], a00, 0, 0, 0);
          a01 = __builtin_amdgcn_mfma_f32_16x16x32_bf16(A[kt], Bf[1][kt], a01, 0, 0, 0);
        }
      }
      {
        bf16x8 A[6];
        #pragma unroll
        for (int kt = 0; kt < 6; kt++)
          A[kt] = *((const bf16x8*)&xh[b][(16 + i)*200 + kt*32 + q*8]);
        #pragma unroll
        for (int kt = 0; kt < 6; kt++){
          a10 = __builtin_amdgcn_mfma_f32_16x16x32_bf16(A[kt], Bf[0][kt], a10, 0, 0, 0);
          a11 = __builtin_amdgcn_mfma_f32_16x16x32_bf16(A[kt], Bf[1][kt], a11, 0, 0, 0);
        }
      }
      // ---- next step's x_emb (depends only on relL) -> xh[b^1] ----
      if (step < 18){
        int tt = step + 2;             // t+1
        float2 rr = *((const float2*)&relL[dm*40 + tt*2]);
        float a0 = fmaxf(0.f, rr.x*eW0[e0]   + rr.y*eW1[e0]   + ebL[e0]);
        float a1 = fmaxf(0.f, rr.x*eW0[e0+1] + rr.y*eW1[e0+1] + ebL[e0+1]);
        *((unsigned int*)&xh[b^1][dm*200 + e0]) = pk_bf16(a0, a1);
      }
    } else {
      // ---- PRED: h-frag reads + W_hh MFMAs overlap the disp reduce ----
      bf16x8 A0[4], A1[4];
      #pragma unroll
      for (int k2 = 0; k2 < 4; k2++){
        A0[k2] = *((const bf16x8*)&xh[b][i*200 + 64 + k2*32 + q*8]);
        A1[k2] = *((const bf16x8*)&xh[b][(16 + i)*200 + 64 + k2*32 + q*8]);
      }

      // disp = h @ pred_W[:, :128].T + imgc + pb ; 32 threads/sample
      bf16x4 hv = *((const bf16x4*)&xh[b][dm*200 + 64 + i32*4]);
      float4 pa = *((const float4*)&pwL[i32*4]);
      float4 pc = *((const float4*)&pwL[128 + i32*4]);
      float h0f = bf2f((unsigned short)hv[0]);
      float h1f = bf2f((unsigned short)hv[1]);
      float h2f_ = bf2f((unsigned short)hv[2]);
      float h3f = bf2f((unsigned short)hv[3]);
      float s0 = h0f*pa.x + h1f*pa.y + h2f_*pa.z + h3f*pa.w;
      float s1 = h0f*pc.x + h1f*pc.y + h2f_*pc.z + h3f*pc.w;

      // W_hh MFMAs (kt 2..5) — independent of the disp reduce
      #pragma unroll
      for (int k2 = 0; k2 < 4; k2++){
        a00 = __builtin_amdgcn_mfma_f32_16x16x32_bf16(A0[k2], Bf[0][k2+2], a00, 0, 0, 0);
        a01 = __builtin_amdgcn_mfma_f32_16x16x32_bf16(A0[k2], Bf[1][k2+2], a01, 0, 0, 0);
        a10 = __builtin_amdgcn_mfma_f32_16x16x32_bf16(A1[k2], Bf[0][k2+2], a10, 0, 0, 0);
        a11 = __builtin_amdgcn_mfma_f32_16x16x32_bf16(A1[k2], Bf[1][k2+2], a11, 0, 0, 0);
      }

      s0 += __shfl_xor(s0, 1);  s1 += __shfl_xor(s1, 1);
      s0 += __shfl_xor(s0, 2);  s1 += __shfl_xor(s1, 2);
      s0 += __shfl_xor(s0, 4);  s1 += __shfl_xor(s1, 4);
      s0 += __shfl_xor(s0, 8);  s1 += __shfl_xor(s1, 8);
      s0 += __shfl_xor(s0, 16); s1 += __shfl_xor(s1, 16);
      float d0 = s0 + imgc0 + pbL[0];
      float d1 = s1 + imgc1 + pbL[1];
      if (i32 < 2){
        pos_r += (i32 == 0) ? d0 : d1;
        out[(size_t)(g0 + dm)*60 + (size_t)(step - 19)*2 + i32] = pos_r;
      }
      float a0 = fmaxf(0.f, d0*eW0[e0]   + d1*eW1[e0]   + ebL[e0]);
      float a1 = fmaxf(0.f, d0*eW0[e0+1] + d1*eW1[e0+1] + ebL[e0+1]);
      *((unsigned int*)&xh[b][dm*200 + e0]) = pk_bf16(a0, a1);

      __syncthreads();   // barrier2: x_emb visible; only x-part remains
      #pragma unroll
      for (int k2 = 0; k2 < 2; k2++){
        bf16x8 X0 = *((const bf16x8*)&xh[b][i*200 + k2*32 + q*8]);
        bf16x8 X1 = *((const bf16x8*)&xh[b][(16 + i)*200 + k2*32 + q*8]);
        a00 = __builtin_amdgcn_mfma_f32_16x16x32_bf16(X0, Bf[0][k2], a00, 0, 0, 0);
        a01 = __builtin_amdgcn_mfma_f32_16x16x32_bf16(X0, Bf[1][k2], a01, 0, 0, 0);
        a10 = __builtin_amdgcn_mfma_f32_16x16x32_bf16(X1, Bf[0][k2], a10, 0, 0, 0);
        a11 = __builtin_amdgcn_mfma_f32_16x16x32_bf16(X1, Bf[1][k2], a11, 0, 0, 0);
      }
    }

    // ---- par-selection via vector ternaries (static indexing only) ----
    f32x4 self0 = par ? a10 : a00;
    f32x4 self1 = par ? a11 : a01;
    f32x4 send0 = par ? a00 : a10;
    f32x4 send1 = par ? a01 : a11;

    // ---- gate exchange (lanes i <-> i^1) + nonlinearity (exp) ----
    float h2f[4];
    #pragma unroll
    for (int r = 0; r < 4; r++){
      float y0 = __shfl_xor(send0[r], 1);
      float y1 = __shfl_xor(send1[r], 1);
      float a0 = self0[r];
      float a1 = self1[r];
      float ig = par ? y0 : a0;
      float fg = par ? a0 : y0;
      float gg = par ? y1 : a1;
      float og = par ? a1 : y1;
      float c2 = sigm(fg)*c_s[r] + sigm(ig)*tanh_(gg);
      float h2 = sigm(og)*tanh_(c2);
      if (obs){
        int thr = (int)((thrpk >> (8*r)) & 0xFFu);
        if (step < thr) c2 = c_s[r];           // c masked-keep
      }
      c_s[r] = c2;
      h2f[r] = h2;
    }

    // ---- 4x8 in-register transpose -> single ds_write_b64 ----
    unsigned int P0 = pk_bf16(h2f[0], h2f[1]);
    unsigned int P1 = pk_bf16(h2f[2], h2f[3]);
    unsigned int X0 = __shfl_xor(P0, 2);
    unsigned int X1 = __shfl_xor(P1, 2);
    P0 = __builtin_amdgcn_perm(X0, P0, selA);
    P1 = __builtin_amdgcn_perm(X1, P1, selA);
    unsigned int Z0 = __shfl_xor(P0, 4);
    unsigned int Z1 = __shfl_xor(P1, 4);
    unsigned int Q0 = (jj & 2) ? Z1 : P0;
    unsigned int Q1 = (jj & 2) ? P1 : Z0;
    if (obs && (step < thr_post)){
      // h masked-keep: old packed pair still lives in xh[b] at wofs
      uint2 oldp = *((const uint2*)&xh[b][wofs]);
      Q0 = oldp.x; Q1 = oldp.y;
    }
    *((uint2*)&xh[b^1][wofs]) = make_uint2(Q0, Q1);

    b ^= 1;
  }
}

extern "C" void kernel_launch(void* const* d_in, const int* in_sizes, int n_in,
                              void* d_out, int out_size, void* d_ws, size_t ws_size,
                              hipStream_t stream){
  const float* img     = (const float*)d_in[0];
  const float* obs_pos = (const float*)d_in[1];
  const int*   hist    = (const int*)d_in[2];
  const float* rel     = (const float*)d_in[3];
  const float* h0      = (const float*)d_in[4];
  const float* W_ih    = (const float*)d_in[5];
  const float* W_hh    = (const float*)d_in[6];
  const float* b_ih    = (const float*)d_in[7];
  const float* b_hh    = (const float*)d_in[8];
  const float* eW      = (const float*)d_in[9];
  const float* eb      = (const float*)d_in[10];
  const float* pW      = (const float*)d_in[11];
  const float* pb      = (const float*)d_in[12];
  float* out = (float*)d_out;
  hipLaunchKernelGGL(traj_kernel, dim3(8192/MBLK), dim3(1024), 0, stream,
                     img, obs_pos, hist, rel, h0, W_ih, W_hh, b_ih, b_hh,
                     eW, eb, pW, pb, out);
}

// Round 8
// 255.222 us; speedup vs baseline: 1.3374x; 1.1633x over previous
//
#include <hip/hip_runtime.h>

#define MBLK 32

typedef __attribute__((ext_vector_type(8))) short bf16x8;
typedef __attribute__((ext_vector_type(16))) float f32x16;

__device__ __forceinline__ unsigned short f2bf(float x){
  unsigned int u = __float_as_uint(x);
  u = u + 0x7FFFu + ((u >> 16) & 1u);
  return (unsigned short)(u >> 16);
}
__device__ __forceinline__ float bf2f(unsigned short s){
  return __uint_as_float(((unsigned int)s) << 16);
}
__device__ __forceinline__ float sigm(float x){
  return __builtin_amdgcn_rcpf(1.0f + __expf(-x));
}
__device__ __forceinline__ float tanh_(float x){
  return 1.0f - 2.0f*__builtin_amdgcn_rcpf(__expf(2.0f*x) + 1.0f);
}
// pack 2 f32 -> 2 bf16 (RNE), lo = first operand
__device__ __forceinline__ unsigned int pk_bf16(float lo, float hi){
  unsigned int r;
  asm("v_cvt_pk_bf16_f32 %0, %1, %2" : "=v"(r) : "v"(lo), "v"(hi));
  return r;
}

// 512-thread block, 8 waves, MBLK=32, 256 blocks = 1 block/CU,
// __launch_bounds__(512,2) -> <=256 VGPR, 2 waves/SIMD.
// Gate GEMM via mfma_f32_32x32x16_bf16 with WEIGHTS on the A(M)-side and
// ACTIVATIONS on the B(N)-side: C col=lane&31 = sample, C row-formula =
// permuted gate row [m74/m101]. Wave wv owns hidden wv*16..+15; tile T
// rows = [gate T*2 (h0..15) | gate T*2+1 (h0..15)]. Each lane ends with
// all 4 gates x 8 hidden x ONE sample -> nonlin is lane-local (no
// shuffles, no transpose); h-write = 2 contiguous ds_write_b64.
// Bias folded into MFMA as 13th K-step (B-side const-1 column in regs,
// bias row in A-side weight frag) -> no per-step bias handling.
// K layout per row (200-short stride): [x 0..63 | h 64..191 | pad].
// Pred-step split kept: W_hh MFMAs overlap disp reduce; x-part after
// barrier2. Obs: single barrier + x_emb lookahead.
// vs unbenched r7 source: obs sweep split into 2x6 K-steps to cap peak
// VGPR (spill was the r1/r4 failure mode).
__global__ __launch_bounds__(512, 2) void traj_kernel(
    const float* __restrict__ img, const float* __restrict__ obs_pos,
    const int* __restrict__ hist, const float* __restrict__ rel,
    const float* __restrict__ h0, const float* __restrict__ W_ih,
    const float* __restrict__ W_hh, const float* __restrict__ b_ih,
    const float* __restrict__ b_hh, const float* __restrict__ eW,
    const float* __restrict__ eb, const float* __restrict__ pW,
    const float* __restrict__ pb, float* __restrict__ out)
{
  __shared__ unsigned short xh[2][MBLK*200];
  __shared__ float relL[MBLK*40];
  __shared__ float pwL[256];          // pred_W[:, :128]
  __shared__ float imgcL[MBLK*2];

  const int tid   = threadIdx.x;
  const int wv    = tid >> 6;          // 0..7
  const int lane  = tid & 63;
  const int m     = lane & 31;         // sample owned by this lane (MFMA N-col)
  const int khalf = lane >> 5;         // K-half within a 16-K step
  const int hb    = khalf*4;           // hidden sub-offset
  const int g0    = blockIdx.x * MBLK;
  const int dm    = tid >> 4;          // sample 0..31 (16 threads/sample)
  const int i16   = tid & 15;

  // ---- cooperative staging ----
  for (int idx = tid; idx < MBLK*40; idx += 512) relL[idx] = rel[g0*40 + idx];
  if (tid < 256) pwL[tid] = pW[(tid >> 7)*2176 + (tid & 127)];

  // ---- img_embedding @ pred_W[:,128:].T  (once; constant over pred steps) ----
  {
    const float* row = img + (size_t)(g0 + dm)*2048 + i16*128;
    const float* p0  = pW + 128 + i16*128;
    const float* p1  = pW + 2176 + 128 + i16*128;
    float s0 = 0.f, s1 = 0.f;
    #pragma unroll
    for (int v = 0; v < 32; v++){
      float4 a  = ((const float4*)row)[v];
      float4 w0 = ((const float4*)p0)[v];
      float4 w1 = ((const float4*)p1)[v];
      s0 += a.x*w0.x + a.y*w0.y + a.z*w0.z + a.w*w0.w;
      s1 += a.x*w1.x + a.y*w1.y + a.z*w1.z + a.w*w1.w;
    }
    #pragma unroll
    for (int msk = 1; msk < 16; msk <<= 1){
      s0 += __shfl_xor(s0, msk);
      s1 += __shfl_xor(s1, msk);
    }
    if (i16 == 0){ imgcL[dm*2] = s0; imgcL[dm*2+1] = s1; }
  }

  // ---- hoisted loop invariants (registers; 2 waves/SIMD = 256 VGPR cap) ----
  const int   e0  = i16*4;             // embed dims owned in x_emb phases
  const float wA0 = eW[e0*2],       wB0 = eW[e0*2+1];
  const float wA1 = eW[(e0+1)*2],   wB1 = eW[(e0+1)*2+1];
  const float wA2 = eW[(e0+2)*2],   wB2 = eW[(e0+2)*2+1];
  const float wA3 = eW[(e0+3)*2],   wB3 = eW[(e0+3)*2+1];
  const float be0 = eb[e0], be1 = eb[e0+1], be2 = eb[e0+2], be3 = eb[e0+3];
  const float pb0r = pb[0], pb1r = pb[1];

  // ---- per-lane persistent state: 8 (hidden, sample m) slots ----
  const int thr = 20 - hist[g0 + m];   // mask threshold, one sample/lane
  float c_s[8];
  #pragma unroll
  for (int t = 0; t < 8; t++) c_s[t] = h0[wv*16 + hb + (t&3) + 8*(t>>2)];

  // ---- initial h state into xh[0] (8 values/thread, prologue only) ----
  {
    int mm = tid >> 4, j8 = (tid & 15)*8;
    #pragma unroll
    for (int e = 0; e < 8; e++)
      xh[0][mm*200 + 64 + j8 + e] = f2bf(h0[j8 + e]);
  }

  // ---- weight A-fragments (M-side), fp32 -> bf16, register-resident ----
  // tile T row p = lane&31: gate = T*2 + (p>>4), hidden = wv*16 + (p&15)
  bf16x8 Bf[2][13];
  #pragma unroll
  for (int T = 0; T < 2; T++){
    int nrow = (T*2 + (m >> 4))*128 + wv*16 + (m & 15);
    #pragma unroll
    for (int ks = 0; ks < 12; ks++){
      const float* src = (ks < 4) ? (W_ih + nrow*64  + ks*16     + khalf*8)
                                  : (W_hh + nrow*128 + (ks-4)*16 + khalf*8);
      float4 lo = ((const float4*)src)[0];
      float4 hi = ((const float4*)src)[1];
      bf16x8 tf;
      tf[0]=(short)f2bf(lo.x); tf[1]=(short)f2bf(lo.y); tf[2]=(short)f2bf(lo.z); tf[3]=(short)f2bf(lo.w);
      tf[4]=(short)f2bf(hi.x); tf[5]=(short)f2bf(hi.y); tf[6]=(short)f2bf(hi.z); tf[7]=(short)f2bf(hi.w);
      Bf[T][ks] = tf;
    }
    // ks 12: bias column (k=192 exactly -> khalf 0, elem 0)
    bf16x8 bb;
    #pragma unroll
    for (int e = 0; e < 8; e++) bb[e] = 0;
    if (khalf == 0) bb[0] = (short)f2bf(b_ih[nrow] + b_hh[nrow]);
    Bf[T][12] = bb;
  }
  // B-side const-1 column for the bias K-step
  bf16x8 Bone;
  #pragma unroll
  for (int e = 0; e < 8; e++) Bone[e] = 0;
  if (khalf == 0) Bone[0] = (short)0x3F80;   // bf16 1.0

  float pos_r = 0.f;
  if (i16 < 2) pos_r = obs_pos[(size_t)(g0 + dm)*40 + 38 + i16];

  __syncthreads();   // staging (relL, pwL, imgcL) visible

  const float imgc0 = imgcL[dm*2], imgc1 = imgcL[dm*2+1];

  // ---- x_emb(t=1) into xh[0] : 4 embed outputs per thread ----
  {
    float2 rr = *((const float2*)&relL[dm*40 + 2]);
    float a0 = fmaxf(0.f, rr.x*wA0 + rr.y*wB0 + be0);
    float a1 = fmaxf(0.f, rr.x*wA1 + rr.y*wB1 + be1);
    float a2 = fmaxf(0.f, rr.x*wA2 + rr.y*wB2 + be2);
    float a3 = fmaxf(0.f, rr.x*wA3 + rr.y*wB3 + be3);
    *((uint2*)&xh[0][dm*200 + e0]) = make_uint2(pk_bf16(a0,a1), pk_bf16(a2,a3));
  }

  const int hofs = m*200 + 64 + wv*16 + hb;   // this lane's h-write base (shorts)
  int b = 0;

  for (int step = 0; step < 49; step++){
    const bool obs = (step < 19);
    __syncthreads();     // barrier1: prev step's writes into xh[b] visible

    f32x16 a0, a1;
    #pragma unroll
    for (int e = 0; e < 16; e++){ a0[e] = 0.f; a1[e] = 0.f; }

    if (obs){
      // ---- full sweep: bias step + 12 activation K-steps (2x6 to cap VGPR) ----
      a0 = __builtin_amdgcn_mfma_f32_32x32x16_bf16(Bf[0][12], Bone, a0, 0, 0, 0);
      a1 = __builtin_amdgcn_mfma_f32_32x32x16_bf16(Bf[1][12], Bone, a1, 0, 0, 0);
      {
        bf16x8 X[6];
        #pragma unroll
        for (int ks = 0; ks < 6; ks++)
          X[ks] = *((const bf16x8*)&xh[b][m*200 + ks*16 + khalf*8]);
        #pragma unroll
        for (int ks = 0; ks < 6; ks++){
          a0 = __builtin_amdgcn_mfma_f32_32x32x16_bf16(Bf[0][ks], X[ks], a0, 0, 0, 0);
          a1 = __builtin_amdgcn_mfma_f32_32x32x16_bf16(Bf[1][ks], X[ks], a1, 0, 0, 0);
        }
      }
      {
        bf16x8 X[6];
        #pragma unroll
        for (int ks = 0; ks < 6; ks++)
          X[ks] = *((const bf16x8*)&xh[b][m*200 + (6+ks)*16 + khalf*8]);
        #pragma unroll
        for (int ks = 0; ks < 6; ks++){
          a0 = __builtin_amdgcn_mfma_f32_32x32x16_bf16(Bf[0][6+ks], X[ks], a0, 0, 0, 0);
          a1 = __builtin_amdgcn_mfma_f32_32x32x16_bf16(Bf[1][6+ks], X[ks], a1, 0, 0, 0);
        }
      }
      // ---- next step's x_emb (depends only on relL) -> xh[b^1] ----
      if (step < 18){
        int tt = step + 2;             // t+1
        float2 rr = *((const float2*)&relL[dm*40 + tt*2]);
        float x0 = fmaxf(0.f, rr.x*wA0 + rr.y*wB0 + be0);
        float x1 = fmaxf(0.f, rr.x*wA1 + rr.y*wB1 + be1);
        float x2 = fmaxf(0.f, rr.x*wA2 + rr.y*wB2 + be2);
        float x3 = fmaxf(0.f, rr.x*wA3 + rr.y*wB3 + be3);
        *((uint2*)&xh[b^1][dm*200 + e0]) = make_uint2(pk_bf16(x0,x1), pk_bf16(x2,x3));
      }
    } else {
      // ---- PRED: h-frag reads + W_hh/bias MFMAs overlap the disp reduce ----
      bf16x8 Xh[8];
      #pragma unroll
      for (int ks = 0; ks < 8; ks++)
        Xh[ks] = *((const bf16x8*)&xh[b][m*200 + 64 + ks*16 + khalf*8]);

      // disp = h @ pred_W[:, :128].T + imgc + pb ; 16 threads/sample
      bf16x8 hv = *((const bf16x8*)&xh[b][dm*200 + 64 + i16*8]);
      float4 pa0 = *((const float4*)&pwL[i16*8]);
      float4 pa1 = *((const float4*)&pwL[i16*8 + 4]);
      float4 pc0 = *((const float4*)&pwL[128 + i16*8]);
      float4 pc1 = *((const float4*)&pwL[128 + i16*8 + 4]);
      float s0, s1;
      {
        float h0f = bf2f((unsigned short)hv[0]), h1f = bf2f((unsigned short)hv[1]);
        float h2f = bf2f((unsigned short)hv[2]), h3f = bf2f((unsigned short)hv[3]);
        float h4f = bf2f((unsigned short)hv[4]), h5f = bf2f((unsigned short)hv[5]);
        float h6f = bf2f((unsigned short)hv[6]), h7f = bf2f((unsigned short)hv[7]);
        s0 = h0f*pa0.x + h1f*pa0.y + h2f*pa0.z + h3f*pa0.w
           + h4f*pa1.x + h5f*pa1.y + h6f*pa1.z + h7f*pa1.w;
        s1 = h0f*pc0.x + h1f*pc0.y + h2f*pc0.z + h3f*pc0.w
           + h4f*pc1.x + h5f*pc1.y + h6f*pc1.z + h7f*pc1.w;
      }

      // W_hh + bias MFMAs — independent of the disp reduce
      a0 = __builtin_amdgcn_mfma_f32_32x32x16_bf16(Bf[0][12], Bone, a0, 0, 0, 0);
      a1 = __builtin_amdgcn_mfma_f32_32x32x16_bf16(Bf[1][12], Bone, a1, 0, 0, 0);
      #pragma unroll
      for (int ks = 0; ks < 8; ks++){
        a0 = __builtin_amdgcn_mfma_f32_32x32x16_bf16(Bf[0][4+ks], Xh[ks], a0, 0, 0, 0);
        a1 = __builtin_amdgcn_mfma_f32_32x32x16_bf16(Bf[1][4+ks], Xh[ks], a1, 0, 0, 0);
      }

      s0 += __shfl_xor(s0, 1);  s1 += __shfl_xor(s1, 1);
      s0 += __shfl_xor(s0, 2);  s1 += __shfl_xor(s1, 2);
      s0 += __shfl_xor(s0, 4);  s1 += __shfl_xor(s1, 4);
      s0 += __shfl_xor(s0, 8);  s1 += __shfl_xor(s1, 8);
      float d0 = s0 + imgc0 + pb0r;
      float d1 = s1 + imgc1 + pb1r;
      if (i16 < 2){
        pos_r += (i16 == 0) ? d0 : d1;
        out[(size_t)(g0 + dm)*60 + (size_t)(step - 19)*2 + i16] = pos_r;
      }
      float x0 = fmaxf(0.f, d0*wA0 + d1*wB0 + be0);
      float x1 = fmaxf(0.f, d0*wA1 + d1*wB1 + be1);
      float x2 = fmaxf(0.f, d0*wA2 + d1*wB2 + be2);
      float x3 = fmaxf(0.f, d0*wA3 + d1*wB3 + be3);
      *((uint2*)&xh[b][dm*200 + e0]) = make_uint2(pk_bf16(x0,x1), pk_bf16(x2,x3));

      __syncthreads();   // barrier2: x_emb visible; only x-part remains
      #pragma unroll
      for (int ks = 0; ks < 4; ks++){
        bf16x8 Xx = *((const bf16x8*)&xh[b][m*200 + ks*16 + khalf*8]);
        a0 = __builtin_amdgcn_mfma_f32_32x32x16_bf16(Bf[0][ks], Xx, a0, 0, 0, 0);
        a1 = __builtin_amdgcn_mfma_f32_32x32x16_bf16(Bf[1][ks], Xx, a1, 0, 0, 0);
      }
    }

    // ---- lane-local nonlinearity: all 4 gates on this lane ----
    // slot t: hidden = wv*16 + hb + (t&3) + 8*(t>>2), sample m
    // ig = a0[t], fg = a0[8+t], gg = a1[t], og = a1[8+t]
    float h2f[8];
    #pragma unroll
    for (int t = 0; t < 8; t++){
      float ig = a0[t];
      float fg = a0[8+t];
      float gg = a1[t];
      float og = a1[8+t];
      float c2 = sigm(fg)*c_s[t] + sigm(ig)*tanh_(gg);
      float h2 = sigm(og)*tanh_(c2);
      if (obs && (step < thr)) c2 = c_s[t];    // c masked-keep
      c_s[t] = c2;
      h2f[t] = h2;
    }

    // ---- h-write: 2 contiguous ds_write_b64 (no transpose needed) ----
    uint2 Qa = make_uint2(pk_bf16(h2f[0], h2f[1]), pk_bf16(h2f[2], h2f[3]));
    uint2 Qb = make_uint2(pk_bf16(h2f[4], h2f[5]), pk_bf16(h2f[6], h2f[7]));
    if (obs && (step < thr)){
      Qa = *((const uint2*)&xh[b][hofs]);      // old h, bit-exact keep
      Qb = *((const uint2*)&xh[b][hofs + 8]);
    }
    *((uint2*)&xh[b^1][hofs])     = Qa;
    *((uint2*)&xh[b^1][hofs + 8]) = Qb;

    b ^= 1;
  }
}

extern "C" void kernel_launch(void* const* d_in, const int* in_sizes, int n_in,
                              void* d_out, int out_size, void* d_ws, size_t ws_size,
                              hipStream_t stream){
  const float* img     = (const float*)d_in[0];
  const float* obs_pos = (const float*)d_in[1];
  const int*   hist    = (const int*)d_in[2];
  const float* rel     = (const float*)d_in[3];
  const float* h0      = (const float*)d_in[4];
  const float* W_ih    = (const float*)d_in[5];
  const float* W_hh    = (const float*)d_in[6];
  const float* b_ih    = (const float*)d_in[7];
  const float* b_hh    = (const float*)d_in[8];
  const float* eW      = (const float*)d_in[9];
  const float* eb      = (const float*)d_in[10];
  const float* pW      = (const float*)d_in[11];
  const float* pb      = (const float*)d_in[12];
  float* out = (float*)d_out;
  hipLaunchKernelGGL(traj_kernel, dim3(8192/MBLK), dim3(512), 0, stream,
                     img, obs_pos, hist, rel, h0, W_ih, W_hh, b_ih, b_hh,
                     eW, eb, pW, pb, out);
}